// Round 17
// baseline (989.854 us; speedup 1.0000x reference)
//
#include <hip/hip_runtime.h>
#include <math.h>

#define NL 2
#define KK 3
#define HIDD 64
#define OUTD 32
#define NB 8
#define NN 10000
#define NE 160000
#define ROWS 80000            // NB*NN;  permuted row index = n*8 + b
#define WSTRIDE (128*HIDD)    // 8192 floats per W[l,d,k]

typedef __attribute__((ext_vector_type(8))) short bf16x8;
typedef __attribute__((ext_vector_type(8))) unsigned short u16x8;
typedef __attribute__((ext_vector_type(4))) unsigned short u16x4;
typedef __attribute__((ext_vector_type(4))) float f32x4;

__device__ __forceinline__ ushort f2b(float x) {
    union { float f; unsigned u; } v; v.f = x;
    unsigned r = (v.u + 0x7fff + ((v.u >> 16) & 1)) >> 16;
    return (ushort)r;
}
__device__ __forceinline__ float b2f(ushort u) {
    union { unsigned u; float f; } v; v.u = (unsigned)u << 16;
    return v.f;
}

// ---------------- setup ----------------
__global__ void zero_kernel(int* p, long n) {
    long t = (long)blockIdx.x * blockDim.x + threadIdx.x;
    if (t < n) p[t] = 0;
}

__global__ void deg_cnt_kernel(const float* __restrict__ w, const int* __restrict__ src,
                               const int* __restrict__ dst, float* deg_out, float* deg_in,
                               int* cnt_f, int* cnt_r) {
    int e = blockIdx.x * blockDim.x + threadIdx.x;
    if (e >= NE) return;
    int s = src[e], d = dst[e];
    float we = w[e];
    atomicAdd(&deg_out[s], we);
    atomicAdd(&deg_in[d], we);
    atomicAdd(&cnt_f[d], 1);
    atomicAdd(&cnt_r[s], 1);
}

__global__ void scan_kernel(const int* __restrict__ cnt, int* __restrict__ off) {
    __shared__ int part[256];
    const int CH = (NN + 255) / 256;
    int t = threadIdx.x;
    int s = 0;
    for (int i = 0; i < CH; ++i) {
        int idx = t * CH + i;
        if (idx < NN) s += cnt[idx];
    }
    part[t] = s;
    __syncthreads();
    if (t == 0) {
        int run = 0;
        for (int i = 0; i < 256; ++i) { int v = part[i]; part[i] = run; run += v; }
        off[NN] = run;
    }
    __syncthreads();
    int run = part[t];
    for (int i = 0; i < CH; ++i) {
        int idx = t * CH + i;
        if (idx < NN) { off[idx] = run; run += cnt[idx]; }
    }
}

__global__ void copy_pos_kernel(const int* __restrict__ off_f, const int* __restrict__ off_r,
                                int* pos_f, int* pos_r) {
    int t = blockIdx.x * blockDim.x + threadIdx.x;
    if (t < NN) { pos_f[t] = off_f[t]; pos_r[t] = off_r[t]; }
}

__global__ void fill_kernel(const float* __restrict__ w, const int* __restrict__ src,
                            const int* __restrict__ dst, const float* __restrict__ deg_out,
                            const float* __restrict__ deg_in,
                            int* pos_f, int* pos_r,
                            int* col_f, float* w_f, int* col_r, float* w_r) {
    int e = blockIdx.x * blockDim.x + threadIdx.x;
    if (e >= NE) return;
    int s = src[e], d = dst[e];
    float we = w[e];
    float dgo = deg_out[s]; dgo = (dgo > 0.f) ? dgo : 1.f;
    float dgi = deg_in[d];  dgi = (dgi > 0.f) ? dgi : 1.f;
    int pf = atomicAdd(&pos_f[d], 1);
    col_f[pf] = s; w_f[pf] = we / dgo;
    int pr = atomicAdd(&pos_r[s], 1);
    col_r[pr] = d; w_r[pr] = we / dgi;
}

// ---------------- converts ----------------
// W[l][d][k][f:128][o:64] fp32 -> Wt[l][g][d][k][o:64][f:128] bf16 (k0 dir-pair folded)
__global__ void convW_kernel(const float* __restrict__ Wz, const float* __restrict__ Wr,
                             const float* __restrict__ Wh, ushort* __restrict__ Wt) {
    int t = blockIdx.x * 256 + threadIdx.x;   // over 589824
    if (t >= 2 * 3 * 2 * 3 * 64 * 128) return;
    int f = t & 127;
    int r1 = t >> 7;
    int o = r1 & 63;
    int r2 = r1 >> 6;
    int k = r2 % 3;
    int r3 = r2 / 3;
    int d = r3 & 1;
    int r4 = r3 >> 1;
    int g = r4 % 3;
    int l = r4 / 3;
    const float* W = (g == 0) ? Wz : (g == 1) ? Wr : Wh;
    float v = W[(((long)(l * 2 + d) * 3 + k) * 128 + f) * 64 + o];
    if (k == 0 && d == 0)
        v += W[(((long)(l * 2 + 1) * 3 + 0) * 128 + f) * 64 + o];
    Wt[t] = f2b(v);
}

// [B][N][64] fp32 -> xh[(n*8+b)*128 + c*64 ..] bf16 (cached stores: heavily re-read).
// When hp != null also emit a permuted fp32 copy for coalesced epilogue reads.
__global__ void convX_perm(const float* __restrict__ in, ushort* __restrict__ xh, int c,
                           float* __restrict__ hp) {
    long t = (long)blockIdx.x * blockDim.x + threadIdx.x;   // over ROWS*16 quads
    if (t >= (long)ROWS * 16) return;
    int q = (int)(t & 15);
    long rowin = t >> 4;            // b*NN + n
    int b = (int)(rowin / NN);
    int n = (int)(rowin - (long)b * NN);
    f32x4 v = __builtin_nontemporal_load((const f32x4*)&in[t * 4]);   // read-once stream
    u16x4 r;
    r.x = f2b(v.x); r.y = f2b(v.y); r.z = f2b(v.z); r.w = f2b(v.w);
    long orow = (long)n * 8 + b;
    *(u16x4*)&xh[orow * 128 + c * 64 + q * 4] = r;
    if (hp) *(f32x4*)&hp[orow * 64 + q * 4] = v;
}

// ---------------- batch-sliced CSR props (identity node order, cached) ----------------
struct PropCfg {
    const ushort* X[2];
    const ushort* base[2];
    const int*    off[2];
    const int*    col[2];
    const float*  w[2];
    ushort*       out[2];
};

template<int HALF, int NDIR>
__global__ __launch_bounds__(128) void prop_slice(PropCfg C, float alpha, float beta) {
    constexpr int LPG = HALF ? 8 : 16;     // lanes per node-group
    constexpr int GPB = 128 / LPG;         // nodes per block (8 full, 16 half)
    int bid = blockIdx.x;
    int b = bid & 7;
    int r = bid >> 3;
    int dir, tile;
    if (NDIR == 2) { dir = r & 1; tile = r >> 1; }
    else           { dir = 0;     tile = r; }
    int g    = threadIdx.x / LPG;
    int lane = threadIdx.x % LPG;
    int n = tile * GPB + g;
    const ushort* X   = C.X[dir];
    const ushort* bas = C.base[dir];
    const int*    off = C.off[dir];
    const int*    col = C.col[dir];
    const float*  w   = C.w[dir];
    ushort*       out = C.out[dir];
    int s = off[n], e = off[n + 1];
    int eo = b * 128 + (HALF ? 64 : 0) + lane * 8;
    float acc[8];
    #pragma unroll
    for (int i = 0; i < 8; ++i) acc[i] = 0.f;
    int j = s;
    for (; j + 2 <= e; j += 2) {
        int c0 = col[j], c1 = col[j + 1];
        float w0 = w[j], w1 = w[j + 1];
        u16x8 v0 = *(const u16x8*)&X[(long)c0 * 1024 + eo];
        u16x8 v1 = *(const u16x8*)&X[(long)c1 * 1024 + eo];
        #pragma unroll
        for (int i = 0; i < 8; ++i) acc[i] = fmaf(b2f(v0[i]), w0, acc[i]);
        #pragma unroll
        for (int i = 0; i < 8; ++i) acc[i] = fmaf(b2f(v1[i]), w1, acc[i]);
    }
    if (j < e) {
        int c = col[j];
        float ww = w[j];
        u16x8 v = *(const u16x8*)&X[(long)c * 1024 + eo];
        #pragma unroll
        for (int i = 0; i < 8; ++i) acc[i] = fmaf(b2f(v[i]), ww, acc[i]);
    }
    long o = (long)n * 1024 + eo;
    #pragma unroll
    for (int i = 0; i < 8; ++i) acc[i] *= alpha;
    if (beta != 0.f) {
        u16x8 bb = *(const u16x8*)&bas[o];
        #pragma unroll
        for (int i = 0; i < 8; ++i) acc[i] = fmaf(beta, b2f(bb[i]), acc[i]);
    }
    u16x8 rr;
    #pragma unroll
    for (int i = 0; i < 8; ++i) rr[i] = f2b(acc[i]);
    *(u16x8*)&out[o] = rr;
}

// ---------------- LDS-staged MFMA 10-term GEMMs, 8-wave blocks ----------------
// 128-row tiles, 2x32KB LDS double buffer, T2 XOR swizzle, issue-early loads.
// 512 threads / 8 waves -> 2 blocks/CU = 16 waves/CU (was 8): cross-wave latency
// hiding for the barrier-synced tile pipeline.
struct GM5 {
    const ushort* Xb[5];    // buffer bases; block tile = Xb + bid*128*128
    const ushort* Wa[10];   // term c*5+t: chunk c of buffer t (gate A)
    const ushort* Wb[10];   // gate B (dual only)
};

template<int DUAL>
__global__ __launch_bounds__(512, 4) void mfma_lds(GM5 A,
        const float* __restrict__ bias0, const float* __restrict__ bias1,
        const float* __restrict__ hp, float* __restrict__ Z,
        ushort* __restrict__ xh, const float* __restrict__ Zg,
        float* __restrict__ outF, int writeF) {
    constexpr int MI = DUAL ? 2 : 1;       // 16-row groups per wave
    __shared__ ushort sx[2][16384];        // 2 x 32KB
    int tid  = threadIdx.x;
    int lane = tid & 63;
    int wid  = tid >> 6;                   // 0..7
    int lr = lane & 15;
    int lk = lane >> 4;
    int gate  = DUAL ? (wid >> 2) : 0;
    int wrow0 = DUAL ? ((wid & 3) * 32) : (wid * 16);

    f32x4 acc[MI][4];
    #pragma unroll
    for (int i = 0; i < MI; ++i)
        #pragma unroll
        for (int j = 0; j < 4; ++j)
            acc[i][j] = (f32x4){0.f, 0.f, 0.f, 0.f};

    u16x8 streg[4];
    auto load_tile = [&](int t) {
        const u16x8* g = (const u16x8*)(A.Xb[t] + (size_t)blockIdx.x * 16384);
        #pragma unroll
        for (int k = 0; k < 4; ++k) streg[k] = g[tid + k * 512];
    };
    auto write_tile = [&](int bi) {
        #pragma unroll
        for (int k = 0; k < 4; ++k) {
            int unit = tid + k * 512;          // 16B unit within 32KB tile
            int row = unit >> 4, c16 = unit & 15;
            int u2 = (row << 4) | (c16 ^ (row & 7));   // T2 swizzle
            *(u16x8*)&sx[bi][u2 << 3] = streg[k];
        }
    };

    load_tile(0);
    write_tile(0);
    __syncthreads();

    int cur = 0;
    #pragma unroll
    for (int t = 0; t < 5; ++t) {
        if (t < 4) load_tile(t + 1);           // issue early: hides under MFMA
        #pragma unroll
        for (int c = 0; c < 2; ++c) {
            const ushort* Wp = DUAL ? (gate ? A.Wb[c * 5 + t] : A.Wa[c * 5 + t])
                                    : A.Wa[c * 5 + t];
            bf16x8 b[2][4];
            #pragma unroll
            for (int ks = 0; ks < 2; ++ks)
                #pragma unroll
                for (int ni = 0; ni < 4; ++ni)
                    b[ks][ni] = *(const bf16x8*)&Wp[(ni * 16 + lr) * 128 +
                                                    ks * 32 + lk * 8];
            #pragma unroll
            for (int ks = 0; ks < 2; ++ks)
                #pragma unroll
                for (int mi = 0; mi < MI; ++mi) {
                    int r = wrow0 + mi * 16 + lr;
                    int c16 = (c << 3) | (ks << 2) | lk;
                    bf16x8 av = *(const bf16x8*)&sx[cur][(r << 7) +
                                                         ((c16 ^ (r & 7)) << 3)];
                    #pragma unroll
                    for (int ni = 0; ni < 4; ++ni)
                        acc[mi][ni] = __builtin_amdgcn_mfma_f32_16x16x32_bf16(
                            av, b[ks][ni], acc[mi][ni], 0, 0, 0);
                }
        }
        if (t < 4) {
            write_tile(cur ^ 1);               // write-late (after compute)
            __syncthreads();                   // one barrier per tile
            cur ^= 1;
        }
    }

    // ---- epilogues ----
    if (DUAL) {
        const float* bias = gate ? bias1 : bias0;
        #pragma unroll
        for (int mi = 0; mi < MI; ++mi) {
            #pragma unroll
            for (int q = 0; q < 4; ++q) {
                long row = (long)blockIdx.x * 128 + wrow0 + mi * 16 + lk * 4 + q;
                #pragma unroll
                for (int ni = 0; ni < 4; ++ni) {
                    int colc = ni * 16 + lr;
                    float v = acc[mi][ni][q] + bias[colc];
                    float sg = 1.f / (1.f + expf(-v));
                    if (gate == 0) {
                        Z[row * 64 + colc] = sg;
                    } else {
                        float hv = hp[row * 64 + colc];
                        xh[row * 128 + 64 + colc] = f2b(sg * hv);
                    }
                }
            }
        }
    } else {
        #pragma unroll
        for (int mi = 0; mi < MI; ++mi) {
            #pragma unroll
            for (int q = 0; q < 4; ++q) {
                long row = (long)blockIdx.x * 128 + wrow0 + mi * 16 + lk * 4 + q;
                #pragma unroll
                for (int ni = 0; ni < 4; ++ni) {
                    int colc = ni * 16 + lr;
                    float v = acc[mi][ni][q] + bias0[colc];
                    float ht = tanhf(v);
                    float z = Zg[row * 64 + colc];
                    float hv = hp[row * 64 + colc];
                    float res = z * hv + (1.f - z) * ht;
                    if (writeF) outF[row * 64 + colc] = res;
                    else        xh[row * 128 + colc] = f2b(res);
                }
            }
        }
    }
}

// ---------------- final projection 64 -> 32 (permuted input rows) ----------------
__global__ void proj_kernel(const float* __restrict__ last, const float* __restrict__ W,
                            const float* __restrict__ bias, float* __restrict__ out) {
    long t = (long)blockIdx.x * blockDim.x + threadIdx.x;
    if (t >= (long)ROWS * OUTD) return;
    long row = t >> 5;              // n*8 + b
    int  o   = (int)(t & 31);
    int n = (int)(row >> 3), b = (int)(row & 7);
    float acc = bias[o];
    #pragma unroll
    for (int hh = 0; hh < HIDD; ++hh)
        acc = fmaf(last[row * 64 + hh], W[hh * OUTD + o], acc);
    out[((long)b * NN + n) * 32 + o] = acc;
}

extern "C" void kernel_launch(void* const* d_in, const int* in_sizes, int n_in,
                              void* d_out, int out_size, void* d_ws, size_t ws_size,
                              hipStream_t stream) {
    const float* edge_weight = (const float*)d_in[0];
    const float* hidden      = (const float*)d_in[1];
    const float* go_input    = (const float*)d_in[2];
    const float* Wz = (const float*)d_in[3];
    const float* bz = (const float*)d_in[4];
    const float* Wr = (const float*)d_in[5];
    const float* br = (const float*)d_in[6];
    const float* Wh = (const float*)d_in[7];
    const float* bh = (const float*)d_in[8];
    const float* projW = (const float*)d_in[9];
    const float* projb = (const float*)d_in[10];
    const int*   eidx  = (const int*)d_in[11];
    const int* src = eidx;
    const int* dst = eidx + NE;
    float* out = (float*)d_out;

    // ---- workspace ----
    char* p = (char*)d_ws;
    auto alloc = [&](size_t bytes) { char* r = p; p += (bytes + 15) & ~(size_t)15; return r; };
    float* deg_out = (float*)alloc(NN * 4);
    float* deg_in  = (float*)alloc(NN * 4);
    int*   cnt_f   = (int*)alloc(NN * 4);
    int*   cnt_r   = (int*)alloc(NN * 4);
    int*   off_f   = (int*)alloc((NN + 4) * 4);
    int*   off_r   = (int*)alloc((NN + 4) * 4);
    int*   pos_f   = (int*)alloc(NN * 4);
    int*   pos_r   = (int*)alloc(NN * 4);
    int*   col_f   = (int*)alloc(NE * 4);
    float* w_f     = (float*)alloc(NE * 4);
    int*   col_r   = (int*)alloc(NE * 4);
    float* w_r     = (float*)alloc(NE * 4);
    ushort* Wt     = (ushort*)alloc((size_t)2 * 3 * 2 * 3 * 64 * 128 * 2);
    const size_t XB = (size_t)ROWS * 128 * 2;   // 20.48 MB (128-wide bf16)
    ushort* xh  = (ushort*)alloc(XB);
    ushort* Tf1 = (ushort*)alloc(XB);
    ushort* Tf2 = (ushort*)alloc(XB);
    ushort* Tr1 = (ushort*)alloc(XB);
    ushort* Tr2 = (ushort*)alloc(XB);
    float*  Zbuf = (float*)alloc((size_t)ROWS * HIDD * 4);
    float*  hp   = (float*)alloc((size_t)ROWS * HIDD * 4);   // permuted fp32 h
    if ((size_t)(p - (char*)d_ws) > ws_size) return;

    const int TB = 256;
    const int EGRID = (NE + TB - 1) / TB;
    const int NGRID = (NN + TB - 1) / TB;

    // ---- CSR build ----
    zero_kernel<<<(4 * NN + TB - 1) / TB, TB, 0, stream>>>((int*)deg_out, 4 * NN);
    deg_cnt_kernel<<<EGRID, TB, 0, stream>>>(edge_weight, src, dst, deg_out, deg_in, cnt_f, cnt_r);
    scan_kernel<<<1, 256, 0, stream>>>(cnt_f, off_f);
    scan_kernel<<<1, 256, 0, stream>>>(cnt_r, off_r);
    copy_pos_kernel<<<NGRID, TB, 0, stream>>>(off_f, off_r, pos_f, pos_r);
    fill_kernel<<<EGRID, TB, 0, stream>>>(edge_weight, src, dst, deg_out, deg_in,
                                          pos_f, pos_r, col_f, w_f, col_r, w_r);

    convW_kernel<<<2304, 256, 0, stream>>>(Wz, Wr, Wh, Wt);
    convX_perm<<<5000, 256, 0, stream>>>(go_input, xh, 0, nullptr);

    auto wt_term = [&](int l, int g, int d, int k, int c) -> const ushort* {
        return Wt + ((((long)((l * 3 + g) * 2 + d) * 3 + k) * 64) * 128) + (long)c * 64;
    };
    const int dd[5]  = {0, 0, 0, 1, 1};
    const int kk2[5] = {0, 1, 2, 1, 2};

    for (int l = 0; l < NL; ++l) {
        const float* h = hidden + (long)l * ROWS * HIDD;
        convX_perm<<<5000, 256, 0, stream>>>(h, xh, 1, hp);

        // ---- full diffusion of xh ----
        {
            PropCfg c1{};
            c1.X[0] = xh;  c1.off[0] = off_f; c1.col[0] = col_f; c1.w[0] = w_f; c1.out[0] = Tf1;
            c1.X[1] = xh;  c1.off[1] = off_r; c1.col[1] = col_r; c1.w[1] = w_r; c1.out[1] = Tr1;
            prop_slice<0, 2><<<(NN / 8) * 2 * 8, 128, 0, stream>>>(c1, 1.f, 0.f);
            PropCfg c2f{};
            c2f.X[0] = Tf1; c2f.base[0] = xh;
            c2f.off[0] = off_f; c2f.col[0] = col_f; c2f.w[0] = w_f; c2f.out[0] = Tf2;
            prop_slice<0, 1><<<(NN / 8) * 8, 128, 0, stream>>>(c2f, 2.f, -1.f);
            PropCfg c2r{};
            c2r.X[0] = Tr1; c2r.base[0] = xh;
            c2r.off[0] = off_r; c2r.col[0] = col_r; c2r.w[0] = w_r; c2r.out[0] = Tr2;
            prop_slice<0, 1><<<(NN / 8) * 8, 128, 0, stream>>>(c2r, 2.f, -1.f);
        }

        const ushort* xs[5] = {xh, Tf1, Tf2, Tr1, Tr2};
        GM5 A{};
        for (int i = 0; i < 5; ++i) {
            A.Xb[i] = xs[i];
            A.Wa[i]     = wt_term(l, 0, dd[i], kk2[i], 0);
            A.Wa[5 + i] = wt_term(l, 0, dd[i], kk2[i], 1);
            A.Wb[i]     = wt_term(l, 1, dd[i], kk2[i], 0);
            A.Wb[5 + i] = wt_term(l, 1, dd[i], kk2[i], 1);
        }
        mfma_lds<1><<<ROWS / 128, 512, 0, stream>>>(A, bz + l * HIDD, br + l * HIDD,
                                                    hp, Zbuf, xh, nullptr, nullptr, 0);

        // ---- half diffusion of rh (chunk-1 halves) ----
        {
            PropCfg c1{};
            c1.X[0] = xh;  c1.off[0] = off_f; c1.col[0] = col_f; c1.w[0] = w_f; c1.out[0] = Tf1;
            c1.X[1] = xh;  c1.off[1] = off_r; c1.col[1] = col_r; c1.w[1] = w_r; c1.out[1] = Tr1;
            prop_slice<1, 2><<<(NN / 16) * 2 * 8, 128, 0, stream>>>(c1, 1.f, 0.f);
            PropCfg c2{};
            c2.X[0] = Tf1; c2.base[0] = xh;
            c2.off[0] = off_f; c2.col[0] = col_f; c2.w[0] = w_f; c2.out[0] = Tf2;
            c2.X[1] = Tr1; c2.base[1] = xh;
            c2.off[1] = off_r; c2.col[1] = col_r; c2.w[1] = w_r; c2.out[1] = Tr2;
            prop_slice<1, 2><<<(NN / 16) * 2 * 8, 128, 0, stream>>>(c2, 2.f, -1.f);
        }

        GM5 Ah{};
        for (int i = 0; i < 5; ++i) {
            Ah.Xb[i] = xs[i];
            Ah.Wa[i]     = wt_term(l, 2, dd[i], kk2[i], 0);
            Ah.Wa[5 + i] = wt_term(l, 2, dd[i], kk2[i], 1);
        }
        mfma_lds<0><<<ROWS / 128, 512, 0, stream>>>(Ah, bh + l * HIDD, nullptr,
                                                    hp, nullptr, xh, Zbuf, Zbuf,
                                                    (l == NL - 1) ? 1 : 0);
    }

    proj_kernel<<<(int)(((long)ROWS * OUTD + TB - 1) / TB), TB, 0, stream>>>(
        Zbuf, projW, projb, out);
}

// Round 18
// 956.006 us; speedup vs baseline: 1.0354x; 1.0354x over previous
//
#include <hip/hip_runtime.h>
#include <math.h>

#define NL 2
#define KK 3
#define HIDD 64
#define OUTD 32
#define NB 8
#define NN 10000
#define NE 160000
#define ROWS 80000            // NB*NN;  permuted row index = n*8 + b
#define WSTRIDE (128*HIDD)    // 8192 floats per W[l,d,k]

typedef __attribute__((ext_vector_type(8))) short bf16x8;
typedef __attribute__((ext_vector_type(8))) unsigned short u16x8;
typedef __attribute__((ext_vector_type(4))) unsigned short u16x4;
typedef __attribute__((ext_vector_type(4))) float f32x4;

__device__ __forceinline__ ushort f2b(float x) {
    union { float f; unsigned u; } v; v.f = x;
    unsigned r = (v.u + 0x7fff + ((v.u >> 16) & 1)) >> 16;
    return (ushort)r;
}
__device__ __forceinline__ float b2f(ushort u) {
    union { unsigned u; float f; } v; v.u = (unsigned)u << 16;
    return v.f;
}

// ---------------- setup ----------------
__global__ void zero_kernel(int* p, long n) {
    long t = (long)blockIdx.x * blockDim.x + threadIdx.x;
    if (t < n) p[t] = 0;
}

__global__ void deg_cnt_kernel(const float* __restrict__ w, const int* __restrict__ src,
                               const int* __restrict__ dst, float* deg_out, float* deg_in,
                               int* cnt_f, int* cnt_r) {
    int e = blockIdx.x * blockDim.x + threadIdx.x;
    if (e >= NE) return;
    int s = src[e], d = dst[e];
    float we = w[e];
    atomicAdd(&deg_out[s], we);
    atomicAdd(&deg_in[d], we);
    atomicAdd(&cnt_f[d], 1);
    atomicAdd(&cnt_r[s], 1);
}

__global__ void scan_kernel(const int* __restrict__ cnt, int* __restrict__ off) {
    __shared__ int part[256];
    const int CH = (NN + 255) / 256;
    int t = threadIdx.x;
    int s = 0;
    for (int i = 0; i < CH; ++i) {
        int idx = t * CH + i;
        if (idx < NN) s += cnt[idx];
    }
    part[t] = s;
    __syncthreads();
    if (t == 0) {
        int run = 0;
        for (int i = 0; i < 256; ++i) { int v = part[i]; part[i] = run; run += v; }
        off[NN] = run;
    }
    __syncthreads();
    int run = part[t];
    for (int i = 0; i < CH; ++i) {
        int idx = t * CH + i;
        if (idx < NN) { off[idx] = run; run += cnt[idx]; }
    }
}

__global__ void copy_pos_kernel(const int* __restrict__ off_f, const int* __restrict__ off_r,
                                int* pos_f, int* pos_r) {
    int t = blockIdx.x * blockDim.x + threadIdx.x;
    if (t < NN) { pos_f[t] = off_f[t]; pos_r[t] = off_r[t]; }
}

__global__ void fill_kernel(const float* __restrict__ w, const int* __restrict__ src,
                            const int* __restrict__ dst, const float* __restrict__ deg_out,
                            const float* __restrict__ deg_in,
                            int* pos_f, int* pos_r,
                            int* col_f, float* w_f, int* col_r, float* w_r) {
    int e = blockIdx.x * blockDim.x + threadIdx.x;
    if (e >= NE) return;
    int s = src[e], d = dst[e];
    float we = w[e];
    float dgo = deg_out[s]; dgo = (dgo > 0.f) ? dgo : 1.f;
    float dgi = deg_in[d];  dgi = (dgi > 0.f) ? dgi : 1.f;
    int pf = atomicAdd(&pos_f[d], 1);
    col_f[pf] = s; w_f[pf] = we / dgo;
    int pr = atomicAdd(&pos_r[s], 1);
    col_r[pr] = d; w_r[pr] = we / dgi;
}

// ---------------- converts ----------------
// W[l][d][k][f:128][o:64] fp32 -> Wt[l][g][d][k][o:64][f:128] bf16 (k0 dir-pair folded)
__global__ void convW_kernel(const float* __restrict__ Wz, const float* __restrict__ Wr,
                             const float* __restrict__ Wh, ushort* __restrict__ Wt) {
    int t = blockIdx.x * 256 + threadIdx.x;   // over 589824
    if (t >= 2 * 3 * 2 * 3 * 64 * 128) return;
    int f = t & 127;
    int r1 = t >> 7;
    int o = r1 & 63;
    int r2 = r1 >> 6;
    int k = r2 % 3;
    int r3 = r2 / 3;
    int d = r3 & 1;
    int r4 = r3 >> 1;
    int g = r4 % 3;
    int l = r4 / 3;
    const float* W = (g == 0) ? Wz : (g == 1) ? Wr : Wh;
    float v = W[(((long)(l * 2 + d) * 3 + k) * 128 + f) * 64 + o];
    if (k == 0 && d == 0)
        v += W[(((long)(l * 2 + 1) * 3 + 0) * 128 + f) * 64 + o];
    Wt[t] = f2b(v);
}

// [B][N][64] fp32 -> xh[(n*8+b)*128 + c*64 ..] bf16 (cached stores: heavily re-read).
// When hp != null also emit a permuted fp32 copy for coalesced epilogue reads.
__global__ void convX_perm(const float* __restrict__ in, ushort* __restrict__ xh, int c,
                           float* __restrict__ hp) {
    long t = (long)blockIdx.x * blockDim.x + threadIdx.x;   // over ROWS*16 quads
    if (t >= (long)ROWS * 16) return;
    int q = (int)(t & 15);
    long rowin = t >> 4;            // b*NN + n
    int b = (int)(rowin / NN);
    int n = (int)(rowin - (long)b * NN);
    f32x4 v = __builtin_nontemporal_load((const f32x4*)&in[t * 4]);   // read-once stream
    u16x4 r;
    r.x = f2b(v.x); r.y = f2b(v.y); r.z = f2b(v.z); r.w = f2b(v.w);
    long orow = (long)n * 8 + b;
    *(u16x4*)&xh[orow * 128 + c * 64 + q * 4] = r;
    if (hp) *(f32x4*)&hp[orow * 64 + q * 4] = v;
}

// ---------------- batch-sliced CSR props, 2-way edge-split ----------------
// bid%8 == b keeps each XCD's gather slice L2-resident. Within a group, the
// edge list is pair-interleaved across 2 lane-halves (eh): serial chain 8->4
// iterations; halves combined by one shfl_xor per accumulator.
struct PropCfg {
    const ushort* X[2];
    const ushort* base[2];
    const int*    off[2];
    const int*    col[2];
    const float*  w[2];
    ushort*       out[2];
};

template<int HALF, int NDIR>
__global__ __launch_bounds__(128) void prop_slice(PropCfg C, float alpha, float beta) {
    constexpr int LPG = HALF ? 16 : 32;    // lanes per node-group (feat x 2 edge-halves)
    constexpr int FL  = HALF ? 8 : 16;     // feature lanes
    constexpr int GPB = 128 / LPG;         // nodes per block (4 full, 8 half)
    int bid = blockIdx.x;
    int b = bid & 7;
    int r = bid >> 3;
    int dir, tile;
    if (NDIR == 2) { dir = r & 1; tile = r >> 1; }
    else           { dir = 0;     tile = r; }
    int g    = threadIdx.x / LPG;
    int lil  = threadIdx.x % LPG;
    int fl   = lil % FL;
    int eh   = lil / FL;                   // 0 or 1
    int n = tile * GPB + g;
    const ushort* X   = C.X[dir];
    const ushort* bas = C.base[dir];
    const int*    off = C.off[dir];
    const int*    col = C.col[dir];
    const float*  w   = C.w[dir];
    ushort*       out = C.out[dir];
    int s = off[n], e = off[n + 1];
    int eo = b * 128 + (HALF ? 64 : 0) + fl * 8;
    float acc[8];
    #pragma unroll
    for (int i = 0; i < 8; ++i) acc[i] = 0.f;
    int j = s + 2 * eh;
    for (; j + 2 <= e; j += 4) {           // this half's pairs: (j, j+1)
        int c0 = col[j], c1 = col[j + 1];
        float w0 = w[j], w1 = w[j + 1];
        u16x8 v0 = *(const u16x8*)&X[(long)c0 * 1024 + eo];
        u16x8 v1 = *(const u16x8*)&X[(long)c1 * 1024 + eo];
        #pragma unroll
        for (int i = 0; i < 8; ++i) acc[i] = fmaf(b2f(v0[i]), w0, acc[i]);
        #pragma unroll
        for (int i = 0; i < 8; ++i) acc[i] = fmaf(b2f(v1[i]), w1, acc[i]);
    }
    if (j < e) {
        u16x8 v = *(const u16x8*)&X[(long)col[j] * 1024 + eo];
        float ww = w[j];
        #pragma unroll
        for (int i = 0; i < 8; ++i) acc[i] = fmaf(b2f(v[i]), ww, acc[i]);
        if (j + 1 < e) {
            u16x8 v1 = *(const u16x8*)&X[(long)col[j + 1] * 1024 + eo];
            float w1 = w[j + 1];
            #pragma unroll
            for (int i = 0; i < 8; ++i) acc[i] = fmaf(b2f(v1[i]), w1, acc[i]);
        }
    }
    // combine edge-halves: lanes fl and fl+FL hold partial sums
    #pragma unroll
    for (int i = 0; i < 8; ++i) acc[i] += __shfl_xor(acc[i], FL);
    if (eh == 0) {
        long o = (long)n * 1024 + eo;
        #pragma unroll
        for (int i = 0; i < 8; ++i) acc[i] *= alpha;
        if (beta != 0.f) {
            u16x8 bb = *(const u16x8*)&bas[o];
            #pragma unroll
            for (int i = 0; i < 8; ++i) acc[i] = fmaf(beta, b2f(bb[i]), acc[i]);
        }
        u16x8 rr;
        #pragma unroll
        for (int i = 0; i < 8; ++i) rr[i] = f2b(acc[i]);
        *(u16x8*)&out[o] = rr;
    }
}

// ---------------- LDS-staged MFMA 10-term GEMMs, 8-wave blocks ----------------
struct GM5 {
    const ushort* Xb[5];    // buffer bases; block tile = Xb + bid*128*128
    const ushort* Wa[10];   // term c*5+t: chunk c of buffer t (gate A)
    const ushort* Wb[10];   // gate B (dual only)
};

template<int DUAL>
__global__ __launch_bounds__(512, 4) void mfma_lds(GM5 A,
        const float* __restrict__ bias0, const float* __restrict__ bias1,
        const float* __restrict__ hp, float* __restrict__ Z,
        ushort* __restrict__ xh, const float* __restrict__ Zg,
        float* __restrict__ outF, int writeF) {
    constexpr int MI = DUAL ? 2 : 1;       // 16-row groups per wave
    __shared__ ushort sx[2][16384];        // 2 x 32KB
    int tid  = threadIdx.x;
    int lane = tid & 63;
    int wid  = tid >> 6;                   // 0..7
    int lr = lane & 15;
    int lk = lane >> 4;
    int gate  = DUAL ? (wid >> 2) : 0;
    int wrow0 = DUAL ? ((wid & 3) * 32) : (wid * 16);

    f32x4 acc[MI][4];
    #pragma unroll
    for (int i = 0; i < MI; ++i)
        #pragma unroll
        for (int j = 0; j < 4; ++j)
            acc[i][j] = (f32x4){0.f, 0.f, 0.f, 0.f};

    u16x8 streg[4];
    auto load_tile = [&](int t) {
        const u16x8* g = (const u16x8*)(A.Xb[t] + (size_t)blockIdx.x * 16384);
        #pragma unroll
        for (int k = 0; k < 4; ++k) streg[k] = g[tid + k * 512];
    };
    auto write_tile = [&](int bi) {
        #pragma unroll
        for (int k = 0; k < 4; ++k) {
            int unit = tid + k * 512;          // 16B unit within 32KB tile
            int row = unit >> 4, c16 = unit & 15;
            int u2 = (row << 4) | (c16 ^ (row & 7));   // T2 swizzle
            *(u16x8*)&sx[bi][u2 << 3] = streg[k];
        }
    };

    load_tile(0);
    write_tile(0);
    __syncthreads();

    int cur = 0;
    #pragma unroll
    for (int t = 0; t < 5; ++t) {
        if (t < 4) load_tile(t + 1);           // issue early: hides under MFMA
        #pragma unroll
        for (int c = 0; c < 2; ++c) {
            const ushort* Wp = DUAL ? (gate ? A.Wb[c * 5 + t] : A.Wa[c * 5 + t])
                                    : A.Wa[c * 5 + t];
            bf16x8 b[2][4];
            #pragma unroll
            for (int ks = 0; ks < 2; ++ks)
                #pragma unroll
                for (int ni = 0; ni < 4; ++ni)
                    b[ks][ni] = *(const bf16x8*)&Wp[(ni * 16 + lr) * 128 +
                                                    ks * 32 + lk * 8];
            #pragma unroll
            for (int ks = 0; ks < 2; ++ks)
                #pragma unroll
                for (int mi = 0; mi < MI; ++mi) {
                    int r = wrow0 + mi * 16 + lr;
                    int c16 = (c << 3) | (ks << 2) | lk;
                    bf16x8 av = *(const bf16x8*)&sx[cur][(r << 7) +
                                                         ((c16 ^ (r & 7)) << 3)];
                    #pragma unroll
                    for (int ni = 0; ni < 4; ++ni)
                        acc[mi][ni] = __builtin_amdgcn_mfma_f32_16x16x32_bf16(
                            av, b[ks][ni], acc[mi][ni], 0, 0, 0);
                }
        }
        if (t < 4) {
            write_tile(cur ^ 1);               // write-late (after compute)
            __syncthreads();                   // one barrier per tile
            cur ^= 1;
        }
    }

    // ---- epilogues ----
    if (DUAL) {
        const float* bias = gate ? bias1 : bias0;
        #pragma unroll
        for (int mi = 0; mi < MI; ++mi) {
            #pragma unroll
            for (int q = 0; q < 4; ++q) {
                long row = (long)blockIdx.x * 128 + wrow0 + mi * 16 + lk * 4 + q;
                #pragma unroll
                for (int ni = 0; ni < 4; ++ni) {
                    int colc = ni * 16 + lr;
                    float v = acc[mi][ni][q] + bias[colc];
                    float sg = 1.f / (1.f + expf(-v));
                    if (gate == 0) {
                        Z[row * 64 + colc] = sg;
                    } else {
                        float hv = hp[row * 64 + colc];
                        xh[row * 128 + 64 + colc] = f2b(sg * hv);
                    }
                }
            }
        }
    } else {
        #pragma unroll
        for (int mi = 0; mi < MI; ++mi) {
            #pragma unroll
            for (int q = 0; q < 4; ++q) {
                long row = (long)blockIdx.x * 128 + wrow0 + mi * 16 + lk * 4 + q;
                #pragma unroll
                for (int ni = 0; ni < 4; ++ni) {
                    int colc = ni * 16 + lr;
                    float v = acc[mi][ni][q] + bias0[colc];
                    float ht = tanhf(v);
                    float z = Zg[row * 64 + colc];
                    float hv = hp[row * 64 + colc];
                    float res = z * hv + (1.f - z) * ht;
                    if (writeF) outF[row * 64 + colc] = res;
                    else        xh[row * 128 + colc] = f2b(res);
                }
            }
        }
    }
}

// ---------------- final projection 64 -> 32 (permuted input rows) ----------------
__global__ void proj_kernel(const float* __restrict__ last, const float* __restrict__ W,
                            const float* __restrict__ bias, float* __restrict__ out) {
    long t = (long)blockIdx.x * blockDim.x + threadIdx.x;
    if (t >= (long)ROWS * OUTD) return;
    long row = t >> 5;              // n*8 + b
    int  o   = (int)(t & 31);
    int n = (int)(row >> 3), b = (int)(row & 7);
    float acc = bias[o];
    #pragma unroll
    for (int hh = 0; hh < HIDD; ++hh)
        acc = fmaf(last[row * 64 + hh], W[hh * OUTD + o], acc);
    out[((long)b * NN + n) * 32 + o] = acc;
}

extern "C" void kernel_launch(void* const* d_in, const int* in_sizes, int n_in,
                              void* d_out, int out_size, void* d_ws, size_t ws_size,
                              hipStream_t stream) {
    const float* edge_weight = (const float*)d_in[0];
    const float* hidden      = (const float*)d_in[1];
    const float* go_input    = (const float*)d_in[2];
    const float* Wz = (const float*)d_in[3];
    const float* bz = (const float*)d_in[4];
    const float* Wr = (const float*)d_in[5];
    const float* br = (const float*)d_in[6];
    const float* Wh = (const float*)d_in[7];
    const float* bh = (const float*)d_in[8];
    const float* projW = (const float*)d_in[9];
    const float* projb = (const float*)d_in[10];
    const int*   eidx  = (const int*)d_in[11];
    const int* src = eidx;
    const int* dst = eidx + NE;
    float* out = (float*)d_out;

    // ---- workspace ----
    char* p = (char*)d_ws;
    auto alloc = [&](size_t bytes) { char* r = p; p += (bytes + 15) & ~(size_t)15; return r; };
    float* deg_out = (float*)alloc(NN * 4);
    float* deg_in  = (float*)alloc(NN * 4);
    int*   cnt_f   = (int*)alloc(NN * 4);
    int*   cnt_r   = (int*)alloc(NN * 4);
    int*   off_f   = (int*)alloc((NN + 4) * 4);
    int*   off_r   = (int*)alloc((NN + 4) * 4);
    int*   pos_f   = (int*)alloc(NN * 4);
    int*   pos_r   = (int*)alloc(NN * 4);
    int*   col_f   = (int*)alloc(NE * 4);
    float* w_f     = (float*)alloc(NE * 4);
    int*   col_r   = (int*)alloc(NE * 4);
    float* w_r     = (float*)alloc(NE * 4);
    ushort* Wt     = (ushort*)alloc((size_t)2 * 3 * 2 * 3 * 64 * 128 * 2);
    const size_t XB = (size_t)ROWS * 128 * 2;   // 20.48 MB (128-wide bf16)
    ushort* xh  = (ushort*)alloc(XB);
    ushort* Tf1 = (ushort*)alloc(XB);
    ushort* Tf2 = (ushort*)alloc(XB);
    ushort* Tr1 = (ushort*)alloc(XB);
    ushort* Tr2 = (ushort*)alloc(XB);
    float*  Zbuf = (float*)alloc((size_t)ROWS * HIDD * 4);
    float*  hp   = (float*)alloc((size_t)ROWS * HIDD * 4);   // permuted fp32 h
    if ((size_t)(p - (char*)d_ws) > ws_size) return;

    const int TB = 256;
    const int EGRID = (NE + TB - 1) / TB;
    const int NGRID = (NN + TB - 1) / TB;

    // ---- CSR build ----
    zero_kernel<<<(4 * NN + TB - 1) / TB, TB, 0, stream>>>((int*)deg_out, 4 * NN);
    deg_cnt_kernel<<<EGRID, TB, 0, stream>>>(edge_weight, src, dst, deg_out, deg_in, cnt_f, cnt_r);
    scan_kernel<<<1, 256, 0, stream>>>(cnt_f, off_f);
    scan_kernel<<<1, 256, 0, stream>>>(cnt_r, off_r);
    copy_pos_kernel<<<NGRID, TB, 0, stream>>>(off_f, off_r, pos_f, pos_r);
    fill_kernel<<<EGRID, TB, 0, stream>>>(edge_weight, src, dst, deg_out, deg_in,
                                          pos_f, pos_r, col_f, w_f, col_r, w_r);

    convW_kernel<<<2304, 256, 0, stream>>>(Wz, Wr, Wh, Wt);
    convX_perm<<<5000, 256, 0, stream>>>(go_input, xh, 0, nullptr);

    auto wt_term = [&](int l, int g, int d, int k, int c) -> const ushort* {
        return Wt + ((((long)((l * 3 + g) * 2 + d) * 3 + k) * 64) * 128) + (long)c * 64;
    };
    const int dd[5]  = {0, 0, 0, 1, 1};
    const int kk2[5] = {0, 1, 2, 1, 2};

    for (int l = 0; l < NL; ++l) {
        const float* h = hidden + (long)l * ROWS * HIDD;
        convX_perm<<<5000, 256, 0, stream>>>(h, xh, 1, hp);

        // ---- full diffusion of xh ----
        {
            PropCfg c1{};
            c1.X[0] = xh;  c1.off[0] = off_f; c1.col[0] = col_f; c1.w[0] = w_f; c1.out[0] = Tf1;
            c1.X[1] = xh;  c1.off[1] = off_r; c1.col[1] = col_r; c1.w[1] = w_r; c1.out[1] = Tr1;
            prop_slice<0, 2><<<(NN / 4) * 2 * 8, 128, 0, stream>>>(c1, 1.f, 0.f);
            PropCfg c2f{};
            c2f.X[0] = Tf1; c2f.base[0] = xh;
            c2f.off[0] = off_f; c2f.col[0] = col_f; c2f.w[0] = w_f; c2f.out[0] = Tf2;
            prop_slice<0, 1><<<(NN / 4) * 8, 128, 0, stream>>>(c2f, 2.f, -1.f);
            PropCfg c2r{};
            c2r.X[0] = Tr1; c2r.base[0] = xh;
            c2r.off[0] = off_r; c2r.col[0] = col_r; c2r.w[0] = w_r; c2r.out[0] = Tr2;
            prop_slice<0, 1><<<(NN / 4) * 8, 128, 0, stream>>>(c2r, 2.f, -1.f);
        }

        const ushort* xs[5] = {xh, Tf1, Tf2, Tr1, Tr2};
        GM5 A{};
        for (int i = 0; i < 5; ++i) {
            A.Xb[i] = xs[i];
            A.Wa[i]     = wt_term(l, 0, dd[i], kk2[i], 0);
            A.Wa[5 + i] = wt_term(l, 0, dd[i], kk2[i], 1);
            A.Wb[i]     = wt_term(l, 1, dd[i], kk2[i], 0);
            A.Wb[5 + i] = wt_term(l, 1, dd[i], kk2[i], 1);
        }
        mfma_lds<1><<<ROWS / 128, 512, 0, stream>>>(A, bz + l * HIDD, br + l * HIDD,
                                                    hp, Zbuf, xh, nullptr, nullptr, 0);

        // ---- half diffusion of rh (chunk-1 halves) ----
        {
            PropCfg c1{};
            c1.X[0] = xh;  c1.off[0] = off_f; c1.col[0] = col_f; c1.w[0] = w_f; c1.out[0] = Tf1;
            c1.X[1] = xh;  c1.off[1] = off_r; c1.col[1] = col_r; c1.w[1] = w_r; c1.out[1] = Tr1;
            prop_slice<1, 2><<<(NN / 8) * 2 * 8, 128, 0, stream>>>(c1, 1.f, 0.f);
            PropCfg c2{};
            c2.X[0] = Tf1; c2.base[0] = xh;
            c2.off[0] = off_f; c2.col[0] = col_f; c2.w[0] = w_f; c2.out[0] = Tf2;
            c2.X[1] = Tr1; c2.base[1] = xh;
            c2.off[1] = off_r; c2.col[1] = col_r; c2.w[1] = w_r; c2.out[1] = Tr2;
            prop_slice<1, 2><<<(NN / 8) * 2 * 8, 128, 0, stream>>>(c2, 2.f, -1.f);
        }

        GM5 Ah{};
        for (int i = 0; i < 5; ++i) {
            Ah.Xb[i] = xs[i];
            Ah.Wa[i]     = wt_term(l, 2, dd[i], kk2[i], 0);
            Ah.Wa[5 + i] = wt_term(l, 2, dd[i], kk2[i], 1);
        }
        mfma_lds<0><<<ROWS / 128, 512, 0, stream>>>(Ah, bh + l * HIDD, nullptr,
                                                    hp, nullptr, xh, Zbuf, Zbuf,
                                                    (l == NL - 1) ? 1 : 0);
    }

    proj_kernel<<<(int)(((long)ROWS * OUTD + TB - 1) / TB), TB, 0, stream>>>(
        Zbuf, projW, projb, out);
}

// Round 19
// 932.191 us; speedup vs baseline: 1.0619x; 1.0255x over previous
//
#include <hip/hip_runtime.h>
#include <math.h>

#define NL 2
#define KK 3
#define HIDD 64
#define OUTD 32
#define NB 8
#define NN 10000
#define NE 160000
#define ROWS 80000            // NB*NN;  permuted row index = n*8 + b
#define WSTRIDE (128*HIDD)    // 8192 floats per W[l,d,k]

typedef __attribute__((ext_vector_type(8))) short bf16x8;
typedef __attribute__((ext_vector_type(8))) unsigned short u16x8;
typedef __attribute__((ext_vector_type(4))) unsigned short u16x4;
typedef __attribute__((ext_vector_type(4))) float f32x4;

__device__ __forceinline__ ushort f2b(float x) {
    union { float f; unsigned u; } v; v.f = x;
    unsigned r = (v.u + 0x7fff + ((v.u >> 16) & 1)) >> 16;
    return (ushort)r;
}
__device__ __forceinline__ float b2f(ushort u) {
    union { unsigned u; float f; } v; v.u = (unsigned)u << 16;
    return v.f;
}

// ---------------- setup ----------------
__global__ void zero_kernel(int* p, long n) {
    long t = (long)blockIdx.x * blockDim.x + threadIdx.x;
    if (t < n) p[t] = 0;
}

__global__ void deg_cnt_kernel(const float* __restrict__ w, const int* __restrict__ src,
                               const int* __restrict__ dst, float* deg_out, float* deg_in,
                               int* cnt_f, int* cnt_r) {
    int e = blockIdx.x * blockDim.x + threadIdx.x;
    if (e >= NE) return;
    int s = src[e], d = dst[e];
    float we = w[e];
    atomicAdd(&deg_out[s], we);
    atomicAdd(&deg_in[d], we);
    atomicAdd(&cnt_f[d], 1);
    atomicAdd(&cnt_r[s], 1);
}

__global__ void scan_kernel(const int* __restrict__ cnt, int* __restrict__ off) {
    __shared__ int part[256];
    const int CH = (NN + 255) / 256;
    int t = threadIdx.x;
    int s = 0;
    for (int i = 0; i < CH; ++i) {
        int idx = t * CH + i;
        if (idx < NN) s += cnt[idx];
    }
    part[t] = s;
    __syncthreads();
    if (t == 0) {
        int run = 0;
        for (int i = 0; i < 256; ++i) { int v = part[i]; part[i] = run; run += v; }
        off[NN] = run;
    }
    __syncthreads();
    int run = part[t];
    for (int i = 0; i < CH; ++i) {
        int idx = t * CH + i;
        if (idx < NN) { off[idx] = run; run += cnt[idx]; }
    }
}

__global__ void copy_pos_kernel(const int* __restrict__ off_f, const int* __restrict__ off_r,
                                int* pos_f, int* pos_r) {
    int t = blockIdx.x * blockDim.x + threadIdx.x;
    if (t < NN) { pos_f[t] = off_f[t]; pos_r[t] = off_r[t]; }
}

__global__ void fill_kernel(const float* __restrict__ w, const int* __restrict__ src,
                            const int* __restrict__ dst, const float* __restrict__ deg_out,
                            const float* __restrict__ deg_in,
                            int* pos_f, int* pos_r,
                            int* col_f, float* w_f, int* col_r, float* w_r) {
    int e = blockIdx.x * blockDim.x + threadIdx.x;
    if (e >= NE) return;
    int s = src[e], d = dst[e];
    float we = w[e];
    float dgo = deg_out[s]; dgo = (dgo > 0.f) ? dgo : 1.f;
    float dgi = deg_in[d];  dgi = (dgi > 0.f) ? dgi : 1.f;
    int pf = atomicAdd(&pos_f[d], 1);
    col_f[pf] = s; w_f[pf] = we / dgo;
    int pr = atomicAdd(&pos_r[s], 1);
    col_r[pr] = d; w_r[pr] = we / dgi;
}

// ---------------- converts ----------------
// W[l][d][k][f:128][o:64] fp32 -> Wt[l][g][d][k][o:64][f:128] bf16.
// Chebyshev fold (T2 buffers now store plain P(T1)):
//   slot(d0,k0) := W(d0,k0)+W(d1,k0) - W(d0,k2) - W(d1,k2)
//   slot(d,k2)  := 2*W(d,k2)
__global__ void convW_kernel(const float* __restrict__ Wz, const float* __restrict__ Wr,
                             const float* __restrict__ Wh, ushort* __restrict__ Wt) {
    int t = blockIdx.x * 256 + threadIdx.x;   // over 589824
    if (t >= 2 * 3 * 2 * 3 * 64 * 128) return;
    int f = t & 127;
    int r1 = t >> 7;
    int o = r1 & 63;
    int r2 = r1 >> 6;
    int k = r2 % 3;
    int r3 = r2 / 3;
    int d = r3 & 1;
    int r4 = r3 >> 1;
    int g = r4 % 3;
    int l = r4 / 3;
    const float* W = (g == 0) ? Wz : (g == 1) ? Wr : Wh;
    auto idx = [&](int dd_, int kk_) {
        return (((long)(l * 2 + dd_) * 3 + kk_) * 128 + f) * 64 + o;
    };
    float v = W[idx(d, k)];
    if (k == 0 && d == 0)
        v += W[idx(1, 0)] - W[idx(0, 2)] - W[idx(1, 2)];
    if (k == 2) v *= 2.f;
    Wt[t] = f2b(v);
}

// [B][N][64] fp32 -> xh[(n*8+b)*128 + c*64 ..] bf16 (cached stores: heavily re-read).
// When hp != null also emit a permuted fp32 copy for coalesced epilogue reads.
__global__ void convX_perm(const float* __restrict__ in, ushort* __restrict__ xh, int c,
                           float* __restrict__ hp) {
    long t = (long)blockIdx.x * blockDim.x + threadIdx.x;   // over ROWS*16 quads
    if (t >= (long)ROWS * 16) return;
    int q = (int)(t & 15);
    long rowin = t >> 4;            // b*NN + n
    int b = (int)(rowin / NN);
    int n = (int)(rowin - (long)b * NN);
    f32x4 v = __builtin_nontemporal_load((const f32x4*)&in[t * 4]);   // read-once stream
    u16x4 r;
    r.x = f2b(v.x); r.y = f2b(v.y); r.z = f2b(v.z); r.w = f2b(v.w);
    long orow = (long)n * 8 + b;
    *(u16x4*)&xh[orow * 128 + c * 64 + q * 4] = r;
    if (hp) *(f32x4*)&hp[orow * 64 + q * 4] = v;
}

// ---------------- batch-sliced CSR props, 2-way edge-split, pure gather ----------------
// out[n] = sum_j w[j] * X[col[j]]   (alpha/beta folded into Wt -- round 19)
struct PropCfg {
    const ushort* X[2];
    const int*    off[2];
    const int*    col[2];
    const float*  w[2];
    ushort*       out[2];
};

template<int HALF, int NDIR>
__global__ __launch_bounds__(128) void prop_slice(PropCfg C) {
    constexpr int LPG = HALF ? 16 : 32;    // lanes per node-group (feat x 2 edge-halves)
    constexpr int FL  = HALF ? 8 : 16;     // feature lanes
    constexpr int GPB = 128 / LPG;         // nodes per block (4 full, 8 half)
    int bid = blockIdx.x;
    int b = bid & 7;
    int r = bid >> 3;
    int dir, tile;
    if (NDIR == 2) { dir = r & 1; tile = r >> 1; }
    else           { dir = 0;     tile = r; }
    int g    = threadIdx.x / LPG;
    int lil  = threadIdx.x % LPG;
    int fl   = lil % FL;
    int eh   = lil / FL;                   // 0 or 1
    int n = tile * GPB + g;
    const ushort* X   = C.X[dir];
    const int*    off = C.off[dir];
    const int*    col = C.col[dir];
    const float*  w   = C.w[dir];
    ushort*       out = C.out[dir];
    int s = off[n], e = off[n + 1];
    int eo = b * 128 + (HALF ? 64 : 0) + fl * 8;
    float acc[8];
    #pragma unroll
    for (int i = 0; i < 8; ++i) acc[i] = 0.f;
    int j = s + 2 * eh;
    for (; j + 2 <= e; j += 4) {           // this half's pairs: (j, j+1)
        int c0 = col[j], c1 = col[j + 1];
        float w0 = w[j], w1 = w[j + 1];
        u16x8 v0 = *(const u16x8*)&X[(long)c0 * 1024 + eo];
        u16x8 v1 = *(const u16x8*)&X[(long)c1 * 1024 + eo];
        #pragma unroll
        for (int i = 0; i < 8; ++i) acc[i] = fmaf(b2f(v0[i]), w0, acc[i]);
        #pragma unroll
        for (int i = 0; i < 8; ++i) acc[i] = fmaf(b2f(v1[i]), w1, acc[i]);
    }
    if (j < e) {
        u16x8 v = *(const u16x8*)&X[(long)col[j] * 1024 + eo];
        float ww = w[j];
        #pragma unroll
        for (int i = 0; i < 8; ++i) acc[i] = fmaf(b2f(v[i]), ww, acc[i]);
        if (j + 1 < e) {
            u16x8 v1 = *(const u16x8*)&X[(long)col[j + 1] * 1024 + eo];
            float w1 = w[j + 1];
            #pragma unroll
            for (int i = 0; i < 8; ++i) acc[i] = fmaf(b2f(v1[i]), w1, acc[i]);
        }
    }
    // combine edge-halves: lanes fl and fl+FL hold partial sums
    #pragma unroll
    for (int i = 0; i < 8; ++i) acc[i] += __shfl_xor(acc[i], FL);
    if (eh == 0) {
        long o = (long)n * 1024 + eo;
        u16x8 rr;
        #pragma unroll
        for (int i = 0; i < 8; ++i) rr[i] = f2b(acc[i]);
        *(u16x8*)&out[o] = rr;
    }
}

// ---------------- LDS-staged MFMA 10-term GEMMs, 8-wave blocks ----------------
struct GM5 {
    const ushort* Xb[5];    // buffer bases; block tile = Xb + bid*128*128
    const ushort* Wa[10];   // term c*5+t: chunk c of buffer t (gate A)
    const ushort* Wb[10];   // gate B (dual only)
};

template<int DUAL>
__global__ __launch_bounds__(512, 4) void mfma_lds(GM5 A,
        const float* __restrict__ bias0, const float* __restrict__ bias1,
        const float* __restrict__ hp, float* __restrict__ Z,
        ushort* __restrict__ xh, const float* __restrict__ Zg,
        float* __restrict__ outF, int writeF) {
    constexpr int MI = DUAL ? 2 : 1;       // 16-row groups per wave
    __shared__ ushort sx[2][16384];        // 2 x 32KB
    int tid  = threadIdx.x;
    int lane = tid & 63;
    int wid  = tid >> 6;                   // 0..7
    int lr = lane & 15;
    int lk = lane >> 4;
    int gate  = DUAL ? (wid >> 2) : 0;
    int wrow0 = DUAL ? ((wid & 3) * 32) : (wid * 16);

    f32x4 acc[MI][4];
    #pragma unroll
    for (int i = 0; i < MI; ++i)
        #pragma unroll
        for (int j = 0; j < 4; ++j)
            acc[i][j] = (f32x4){0.f, 0.f, 0.f, 0.f};

    u16x8 streg[4];
    auto load_tile = [&](int t) {
        const u16x8* g = (const u16x8*)(A.Xb[t] + (size_t)blockIdx.x * 16384);
        #pragma unroll
        for (int k = 0; k < 4; ++k) streg[k] = g[tid + k * 512];
    };
    auto write_tile = [&](int bi) {
        #pragma unroll
        for (int k = 0; k < 4; ++k) {
            int unit = tid + k * 512;          // 16B unit within 32KB tile
            int row = unit >> 4, c16 = unit & 15;
            int u2 = (row << 4) | (c16 ^ (row & 7));   // T2 swizzle
            *(u16x8*)&sx[bi][u2 << 3] = streg[k];
        }
    };

    load_tile(0);
    write_tile(0);
    __syncthreads();

    int cur = 0;
    #pragma unroll
    for (int t = 0; t < 5; ++t) {
        if (t < 4) load_tile(t + 1);           // issue early: hides under MFMA
        #pragma unroll
        for (int c = 0; c < 2; ++c) {
            const ushort* Wp = DUAL ? (gate ? A.Wb[c * 5 + t] : A.Wa[c * 5 + t])
                                    : A.Wa[c * 5 + t];
            bf16x8 b[2][4];
            #pragma unroll
            for (int ks = 0; ks < 2; ++ks)
                #pragma unroll
                for (int ni = 0; ni < 4; ++ni)
                    b[ks][ni] = *(const bf16x8*)&Wp[(ni * 16 + lr) * 128 +
                                                    ks * 32 + lk * 8];
            #pragma unroll
            for (int ks = 0; ks < 2; ++ks)
                #pragma unroll
                for (int mi = 0; mi < MI; ++mi) {
                    int r = wrow0 + mi * 16 + lr;
                    int c16 = (c << 3) | (ks << 2) | lk;
                    bf16x8 av = *(const bf16x8*)&sx[cur][(r << 7) +
                                                         ((c16 ^ (r & 7)) << 3)];
                    #pragma unroll
                    for (int ni = 0; ni < 4; ++ni)
                        acc[mi][ni] = __builtin_amdgcn_mfma_f32_16x16x32_bf16(
                            av, b[ks][ni], acc[mi][ni], 0, 0, 0);
                }
        }
        if (t < 4) {
            write_tile(cur ^ 1);               // write-late (after compute)
            __syncthreads();                   // one barrier per tile
            cur ^= 1;
        }
    }

    // ---- epilogues ----
    if (DUAL) {
        const float* bias = gate ? bias1 : bias0;
        #pragma unroll
        for (int mi = 0; mi < MI; ++mi) {
            #pragma unroll
            for (int q = 0; q < 4; ++q) {
                long row = (long)blockIdx.x * 128 + wrow0 + mi * 16 + lk * 4 + q;
                #pragma unroll
                for (int ni = 0; ni < 4; ++ni) {
                    int colc = ni * 16 + lr;
                    float v = acc[mi][ni][q] + bias[colc];
                    float sg = 1.f / (1.f + expf(-v));
                    if (gate == 0) {
                        Z[row * 64 + colc] = sg;
                    } else {
                        float hv = hp[row * 64 + colc];
                        xh[row * 128 + 64 + colc] = f2b(sg * hv);
                    }
                }
            }
        }
    } else {
        #pragma unroll
        for (int mi = 0; mi < MI; ++mi) {
            #pragma unroll
            for (int q = 0; q < 4; ++q) {
                long row = (long)blockIdx.x * 128 + wrow0 + mi * 16 + lk * 4 + q;
                #pragma unroll
                for (int ni = 0; ni < 4; ++ni) {
                    int colc = ni * 16 + lr;
                    float v = acc[mi][ni][q] + bias0[colc];
                    float ht = tanhf(v);
                    float z = Zg[row * 64 + colc];
                    float hv = hp[row * 64 + colc];
                    float res = z * hv + (1.f - z) * ht;
                    if (writeF) outF[row * 64 + colc] = res;
                    else        xh[row * 128 + colc] = f2b(res);
                }
            }
        }
    }
}

// ---------------- final projection 64 -> 32 (permuted input rows) ----------------
__global__ void proj_kernel(const float* __restrict__ last, const float* __restrict__ W,
                            const float* __restrict__ bias, float* __restrict__ out) {
    long t = (long)blockIdx.x * blockDim.x + threadIdx.x;
    if (t >= (long)ROWS * OUTD) return;
    long row = t >> 5;              // n*8 + b
    int  o   = (int)(t & 31);
    int n = (int)(row >> 3), b = (int)(row & 7);
    float acc = bias[o];
    #pragma unroll
    for (int hh = 0; hh < HIDD; ++hh)
        acc = fmaf(last[row * 64 + hh], W[hh * OUTD + o], acc);
    out[((long)b * NN + n) * 32 + o] = acc;
}

extern "C" void kernel_launch(void* const* d_in, const int* in_sizes, int n_in,
                              void* d_out, int out_size, void* d_ws, size_t ws_size,
                              hipStream_t stream) {
    const float* edge_weight = (const float*)d_in[0];
    const float* hidden      = (const float*)d_in[1];
    const float* go_input    = (const float*)d_in[2];
    const float* Wz = (const float*)d_in[3];
    const float* bz = (const float*)d_in[4];
    const float* Wr = (const float*)d_in[5];
    const float* br = (const float*)d_in[6];
    const float* Wh = (const float*)d_in[7];
    const float* bh = (const float*)d_in[8];
    const float* projW = (const float*)d_in[9];
    const float* projb = (const float*)d_in[10];
    const int*   eidx  = (const int*)d_in[11];
    const int* src = eidx;
    const int* dst = eidx + NE;
    float* out = (float*)d_out;

    // ---- workspace ----
    char* p = (char*)d_ws;
    auto alloc = [&](size_t bytes) { char* r = p; p += (bytes + 15) & ~(size_t)15; return r; };
    float* deg_out = (float*)alloc(NN * 4);
    float* deg_in  = (float*)alloc(NN * 4);
    int*   cnt_f   = (int*)alloc(NN * 4);
    int*   cnt_r   = (int*)alloc(NN * 4);
    int*   off_f   = (int*)alloc((NN + 4) * 4);
    int*   off_r   = (int*)alloc((NN + 4) * 4);
    int*   pos_f   = (int*)alloc(NN * 4);
    int*   pos_r   = (int*)alloc(NN * 4);
    int*   col_f   = (int*)alloc(NE * 4);
    float* w_f     = (float*)alloc(NE * 4);
    int*   col_r   = (int*)alloc(NE * 4);
    float* w_r     = (float*)alloc(NE * 4);
    ushort* Wt     = (ushort*)alloc((size_t)2 * 3 * 2 * 3 * 64 * 128 * 2);
    const size_t XB = (size_t)ROWS * 128 * 2;   // 20.48 MB (128-wide bf16)
    ushort* xh  = (ushort*)alloc(XB);
    ushort* Tf1 = (ushort*)alloc(XB);
    ushort* Tf2 = (ushort*)alloc(XB);
    ushort* Tr1 = (ushort*)alloc(XB);
    ushort* Tr2 = (ushort*)alloc(XB);
    float*  Zbuf = (float*)alloc((size_t)ROWS * HIDD * 4);
    float*  hp   = (float*)alloc((size_t)ROWS * HIDD * 4);   // permuted fp32 h
    if ((size_t)(p - (char*)d_ws) > ws_size) return;

    const int TB = 256;
    const int EGRID = (NE + TB - 1) / TB;
    const int NGRID = (NN + TB - 1) / TB;

    // ---- CSR build ----
    zero_kernel<<<(4 * NN + TB - 1) / TB, TB, 0, stream>>>((int*)deg_out, 4 * NN);
    deg_cnt_kernel<<<EGRID, TB, 0, stream>>>(edge_weight, src, dst, deg_out, deg_in, cnt_f, cnt_r);
    scan_kernel<<<1, 256, 0, stream>>>(cnt_f, off_f);
    scan_kernel<<<1, 256, 0, stream>>>(cnt_r, off_r);
    copy_pos_kernel<<<NGRID, TB, 0, stream>>>(off_f, off_r, pos_f, pos_r);
    fill_kernel<<<EGRID, TB, 0, stream>>>(edge_weight, src, dst, deg_out, deg_in,
                                          pos_f, pos_r, col_f, w_f, col_r, w_r);

    convW_kernel<<<2304, 256, 0, stream>>>(Wz, Wr, Wh, Wt);
    convX_perm<<<5000, 256, 0, stream>>>(go_input, xh, 0, nullptr);

    auto wt_term = [&](int l, int g, int d, int k, int c) -> const ushort* {
        return Wt + ((((long)((l * 3 + g) * 2 + d) * 3 + k) * 64) * 128) + (long)c * 64;
    };
    const int dd[5]  = {0, 0, 0, 1, 1};
    const int kk2[5] = {0, 1, 2, 1, 2};

    for (int l = 0; l < NL; ++l) {
        const float* h = hidden + (long)l * ROWS * HIDD;
        convX_perm<<<5000, 256, 0, stream>>>(h, xh, 1, hp);

        // ---- full diffusion of xh: T1 = P(xh), T2 = P(T1)  (pure gathers) ----
        {
            PropCfg c1{};
            c1.X[0] = xh;  c1.off[0] = off_f; c1.col[0] = col_f; c1.w[0] = w_f; c1.out[0] = Tf1;
            c1.X[1] = xh;  c1.off[1] = off_r; c1.col[1] = col_r; c1.w[1] = w_r; c1.out[1] = Tr1;
            prop_slice<0, 2><<<(NN / 4) * 2 * 8, 128, 0, stream>>>(c1);
            PropCfg c2f{};
            c2f.X[0] = Tf1;
            c2f.off[0] = off_f; c2f.col[0] = col_f; c2f.w[0] = w_f; c2f.out[0] = Tf2;
            prop_slice<0, 1><<<(NN / 4) * 8, 128, 0, stream>>>(c2f);
            PropCfg c2r{};
            c2r.X[0] = Tr1;
            c2r.off[0] = off_r; c2r.col[0] = col_r; c2r.w[0] = w_r; c2r.out[0] = Tr2;
            prop_slice<0, 1><<<(NN / 4) * 8, 128, 0, stream>>>(c2r);
        }

        const ushort* xs[5] = {xh, Tf1, Tf2, Tr1, Tr2};
        GM5 A{};
        for (int i = 0; i < 5; ++i) {
            A.Xb[i] = xs[i];
            A.Wa[i]     = wt_term(l, 0, dd[i], kk2[i], 0);
            A.Wa[5 + i] = wt_term(l, 0, dd[i], kk2[i], 1);
            A.Wb[i]     = wt_term(l, 1, dd[i], kk2[i], 0);
            A.Wb[5 + i] = wt_term(l, 1, dd[i], kk2[i], 1);
        }
        mfma_lds<1><<<ROWS / 128, 512, 0, stream>>>(A, bz + l * HIDD, br + l * HIDD,
                                                    hp, Zbuf, xh, nullptr, nullptr, 0);

        // ---- half diffusion of rh (chunk-1 halves) ----
        {
            PropCfg c1{};
            c1.X[0] = xh;  c1.off[0] = off_f; c1.col[0] = col_f; c1.w[0] = w_f; c1.out[0] = Tf1;
            c1.X[1] = xh;  c1.off[1] = off_r; c1.col[1] = col_r; c1.w[1] = w_r; c1.out[1] = Tr1;
            prop_slice<1, 2><<<(NN / 8) * 2 * 8, 128, 0, stream>>>(c1);
            PropCfg c2{};
            c2.X[0] = Tf1;
            c2.off[0] = off_f; c2.col[0] = col_f; c2.w[0] = w_f; c2.out[0] = Tf2;
            c2.X[1] = Tr1;
            c2.off[1] = off_r; c2.col[1] = col_r; c2.w[1] = w_r; c2.out[1] = Tr2;
            prop_slice<1, 2><<<(NN / 8) * 2 * 8, 128, 0, stream>>>(c2);
        }

        GM5 Ah{};
        for (int i = 0; i < 5; ++i) {
            Ah.Xb[i] = xs[i];
            Ah.Wa[i]     = wt_term(l, 2, dd[i], kk2[i], 0);
            Ah.Wa[5 + i] = wt_term(l, 2, dd[i], kk2[i], 1);
        }
        mfma_lds<0><<<ROWS / 128, 512, 0, stream>>>(Ah, bh + l * HIDD, nullptr,
                                                    hp, nullptr, xh, Zbuf, Zbuf,
                                                    (l == NL - 1) ? 1 : 0);
    }

    proj_kernel<<<(int)(((long)ROWS * OUTD + TB - 1) / TB), TB, 0, stream>>>(
        Zbuf, projW, projb, out);
}